// Round 4
// baseline (437.317 us; speedup 1.0000x reference)
//
#include <hip/hip_runtime.h>
#include <hip/hip_bf16.h>

// Problem: out = lecac_linear(relu(lecac_linear(x, W1, b1)), W2, b2)
//   x: [262144, 256] f32, W1: [512,256], b1: [512], W2: [256,512], b2: [256]
// R4: persistent blocks, 16 tiles each, cross-tile software pipeline.
// R1-R3 were phase-serialized (1 block/CU, all pipes <20% busy): x-load ->
// L1 -> epi -> L2 chained behind barriers with nothing to overlap. Now tile
// i+2's x streams into registers during tile i's MFMA region, staged to LDS
// during the epilogue slot; raw s_barrier (no vmcnt drain) keeps it in flight.

typedef __attribute__((ext_vector_type(8))) short bf16x8;
typedef __attribute__((ext_vector_type(4))) float f32x4;
typedef __attribute__((ext_vector_type(4))) unsigned short us4;

#define D_IN 256
#define D_HID 512
#define D_OUT 256
#define BM 64
#define TILES 16

__device__ __forceinline__ unsigned short f2bf(float f) {
  union { __hip_bfloat16 h; unsigned short u; } c;
  c.h = __float2bfloat16(f);
  return c.u;
}

// ---- prep 1: deterministic f64 partial abs-sums (8 chunks per tensor) ------
__global__ void partial_abs_kernel(const float* __restrict__ W1,
                                   const float* __restrict__ W2,
                                   double* __restrict__ part) {
  const int b = blockIdx.x;                 // 0..15
  const float* W = (b < 8) ? W1 : W2;
  const float* p = W + (b & 7) * 16384;     // 131072 / 8
  double s = 0.0;
  for (int i = threadIdx.x; i < 16384; i += 1024) s += (double)fabsf(p[i]);
  __shared__ double red[1024];
  red[threadIdx.x] = s;
  __syncthreads();
  for (int st = 512; st > 0; st >>= 1) {
    if (threadIdx.x < st) red[threadIdx.x] += red[threadIdx.x + st];
    __syncthreads();
  }
  if (threadIdx.x == 0) part[b] = red[0];
}

// ---- prep 2: quantize codes (exact ints in bf16); finalizes scales inline --
__global__ void quant_kernel(const float* __restrict__ W1,
                             const float* __restrict__ W2,
                             const double* __restrict__ part,
                             unsigned short* __restrict__ w1c,
                             unsigned short* __restrict__ w2c,
                             float* __restrict__ fscales) {
  int idx = blockIdx.x * blockDim.x + threadIdx.x;  // 65536 float4 chunks
  bool is2 = idx >= 32768;
  const float4* src = is2 ? (const float4*)W2 : (const float4*)W1;
  us4* dst = is2 ? (us4*)w2c : (us4*)w1c;
  int i = is2 ? idx - 32768 : idx;
  const double* pp = part + (is2 ? 8 : 0);
  double sum = ((pp[0] + pp[1]) + (pp[2] + pp[3])) + ((pp[4] + pp[5]) + (pp[6] + pp[7]));
  double s = 1.47 * (sum / 131072.0) + 1e-8;
  if (idx == 0) {
    const double* q = part;
    double s0 = 1.47 * ((((q[0]+q[1])+(q[2]+q[3]))+((q[4]+q[5])+(q[6]+q[7]))) / 131072.0) + 1e-8;
    double s1 = 1.47 * ((((q[8]+q[9])+(q[10]+q[11]))+((q[12]+q[13])+(q[14]+q[15]))) / 131072.0) + 1e-8;
    fscales[0] = (float)s0;
    fscales[1] = (float)s1;
  }
  float4 v = src[i];
  us4 o;
  o.x = f2bf((float)fmin(fmax(rint((double)v.x / s), -2.0), 1.0));
  o.y = f2bf((float)fmin(fmax(rint((double)v.y / s), -2.0), 1.0));
  o.z = f2bf((float)fmin(fmax(rint((double)v.z / s), -2.0), 1.0));
  o.w = f2bf((float)fmin(fmax(rint((double)v.w / s), -2.0), 1.0));
  dst[i] = o;
}

// ---------------- fused persistent MLP kernel -------------------------------
// 256 blocks x 512 threads (8 waves); block b owns tiles [16b, 16b+16).
// LDS: xs [64][256] bf16 (32KB) + hs [64][512] bf16 (64KB) = 96KB, no alias.
// Wave wv: L1 owns hidden rows [64wv,64wv+64) (mf=4); L2 owns out cols
// [32wv,32wv+32) (mf2=2). Per tile: 2 barriers; L2(i)+L1(i+1) = one 256-MFMA
// region per wave; x(i+2) register-prefetched inside it.
__launch_bounds__(512, 2)
__global__ void fused_mlp(const float* __restrict__ x,
                          const float* __restrict__ b1,
                          const float* __restrict__ b2,
                          const unsigned short* __restrict__ w1c,
                          const unsigned short* __restrict__ w2c,
                          const float* __restrict__ fscales,
                          float* __restrict__ out) {
  __shared__ unsigned short xs[BM * D_IN];   // 32 KB
  __shared__ unsigned short hs[BM * D_HID];  // 64 KB
  const int t = threadIdx.x;
  const int lane = t & 63;
  const int wv = t >> 6;      // 0..7
  const int l15 = lane & 15;
  const int g = lane >> 4;    // 0..3
  const long tbase = (long)blockIdx.x * TILES;

  const unsigned short* w1p = w1c + (64 * wv + l15) * 256 + g * 8;  // +4096/mf
  const unsigned short* w2p = w2c + (32 * wv + l15) * 512 + g * 8;  // +8192/mf2

  const float s1 = fscales[0];
  const float s2 = fscales[1];

  float4 xv[8];
  f32x4 zero4 = {0.f, 0.f, 0.f, 0.f};
  f32x4 acc1[4][4];
  f32x4 acc2[2][4];
  bf16x8 awL[2][4];   // L1 weight frags, depth-2
  bf16x8 aw2[2][2];   // L2 weight frags, depth-2

  auto loadxv = [&](long tile) {
    const float4* p = (const float4*)x + tile * 4096;
#pragma unroll
    for (int j = 0; j < 8; ++j) xv[j] = p[j * 512 + t];
  };

  auto stage = [&]() {  // xv -> xs, XOR-swizzled (slot ^= row&7)
#pragma unroll
    for (int j = 0; j < 8; ++j) {
      int m = j * 8 + wv;
      int slot = (lane >> 1) ^ (m & 7);
      us4 o;
      o.x = f2bf(xv[j].x); o.y = f2bf(xv[j].y);
      o.z = f2bf(xv[j].z); o.w = f2bf(xv[j].w);
      *(us4*)&xs[m * 256 + slot * 8 + (lane & 1) * 4] = o;
    }
  };

  auto prefL1 = [&]() {  // weight frags for kk=0,1
#pragma unroll
    for (int mf = 0; mf < 4; ++mf) {
      awL[0][mf] = *(const bf16x8*)(w1p + mf * 4096);
      awL[1][mf] = *(const bf16x8*)(w1p + mf * 4096 + 32);
    }
  };
  auto prefL2 = [&]() {
#pragma unroll
    for (int mf = 0; mf < 2; ++mf) {
      aw2[0][mf] = *(const bf16x8*)(w2p + mf * 8192);
      aw2[1][mf] = *(const bf16x8*)(w2p + mf * 8192 + 32);
    }
  };

  auto runL1 = [&]() {  // acc1 = W1c * xs^T  (K=256, 8 steps)
#pragma unroll
    for (int a = 0; a < 4; ++a)
#pragma unroll
      for (int b = 0; b < 4; ++b) acc1[a][b] = zero4;
    bf16x8 bx[2][4];
#pragma unroll
    for (int nf = 0; nf < 4; ++nf) {
      int m = nf * 16 + l15;
      bx[0][nf] = *(const bf16x8*)&xs[m * 256 + (g ^ (m & 7)) * 8];
    }
#pragma unroll
    for (int kk = 0; kk < 8; ++kk) {
      bf16x8 a0 = awL[kk & 1][0], a1 = awL[kk & 1][1];
      bf16x8 a2 = awL[kk & 1][2], a3 = awL[kk & 1][3];
      if (kk + 2 < 8) {
#pragma unroll
        for (int mf = 0; mf < 4; ++mf)
          awL[kk & 1][mf] = *(const bf16x8*)(w1p + mf * 4096 + (kk + 2) * 32);
      }
      if (kk + 1 < 8) {
#pragma unroll
        for (int nf = 0; nf < 4; ++nf) {
          int m = nf * 16 + l15;
          int slot = ((kk + 1) * 4 + g) ^ (m & 7);
          bx[(kk + 1) & 1][nf] = *(const bf16x8*)&xs[m * 256 + slot * 8];
        }
      }
#pragma unroll
      for (int nf = 0; nf < 4; ++nf) {
        acc1[0][nf] = __builtin_amdgcn_mfma_f32_16x16x32_bf16(a0, bx[kk & 1][nf], acc1[0][nf], 0, 0, 0);
        acc1[1][nf] = __builtin_amdgcn_mfma_f32_16x16x32_bf16(a1, bx[kk & 1][nf], acc1[1][nf], 0, 0, 0);
        acc1[2][nf] = __builtin_amdgcn_mfma_f32_16x16x32_bf16(a2, bx[kk & 1][nf], acc1[2][nf], 0, 0, 0);
        acc1[3][nf] = __builtin_amdgcn_mfma_f32_16x16x32_bf16(a3, bx[kk & 1][nf], acc1[3][nf], 0, 0, 0);
      }
    }
  };

  auto epi1 = [&]() {  // hs = relu(s1*acc1 + b1), swizzled
#pragma unroll
    for (int mf = 0; mf < 4; ++mf) {
      int cb = 64 * wv + 16 * mf + g * 4;
      float4 bb = *(const float4*)&b1[cb];
      int slot_base = cb >> 3;
      int half = (g & 1) * 4;
#pragma unroll
      for (int nf = 0; nf < 4; ++nf) {
        int m = nf * 16 + l15;
        f32x4 a = acc1[mf][nf];
        us4 o;
        o.x = f2bf(fmaxf(s1 * a[0] + bb.x, 0.f));
        o.y = f2bf(fmaxf(s1 * a[1] + bb.y, 0.f));
        o.z = f2bf(fmaxf(s1 * a[2] + bb.z, 0.f));
        o.w = f2bf(fmaxf(s1 * a[3] + bb.w, 0.f));
        int slot = slot_base ^ (m & 7);
        *(us4*)&hs[m * 512 + slot * 8 + half] = o;
      }
    }
  };

  auto runL2 = [&]() {  // acc2 = W2c * hs^T  (K=512, 16 steps)
#pragma unroll
    for (int a = 0; a < 2; ++a)
#pragma unroll
      for (int b = 0; b < 4; ++b) acc2[a][b] = zero4;
    bf16x8 bh[2][4];
#pragma unroll
    for (int nf = 0; nf < 4; ++nf) {
      int m = nf * 16 + l15;
      bh[0][nf] = *(const bf16x8*)&hs[m * 512 + (g ^ (m & 7)) * 8];
    }
#pragma unroll
    for (int kk = 0; kk < 16; ++kk) {
      bf16x8 a0 = aw2[kk & 1][0], a1 = aw2[kk & 1][1];
      if (kk + 2 < 16) {
        aw2[kk & 1][0] = *(const bf16x8*)(w2p + (kk + 2) * 32);
        aw2[kk & 1][1] = *(const bf16x8*)(w2p + 8192 + (kk + 2) * 32);
      }
      if (kk + 1 < 16) {
#pragma unroll
        for (int nf = 0; nf < 4; ++nf) {
          int m = nf * 16 + l15;
          int slot = ((kk + 1) * 4 + g) ^ (m & 7);
          bh[(kk + 1) & 1][nf] = *(const bf16x8*)&hs[m * 512 + slot * 8];
        }
      }
#pragma unroll
      for (int nf = 0; nf < 4; ++nf) {
        acc2[0][nf] = __builtin_amdgcn_mfma_f32_16x16x32_bf16(a0, bh[kk & 1][nf], acc2[0][nf], 0, 0, 0);
        acc2[1][nf] = __builtin_amdgcn_mfma_f32_16x16x32_bf16(a1, bh[kk & 1][nf], acc2[1][nf], 0, 0, 0);
      }
    }
  };

  // ---------------- prologue ----------------
  loadxv(tbase);
  stage();
  loadxv(tbase + 1 < tbase + TILES ? tbase + 1 : tbase + TILES - 1);
  prefL1();
  asm volatile("s_waitcnt lgkmcnt(0)" ::: "memory");
  __builtin_amdgcn_s_barrier();
  runL1();  // tile 0

  // ---------------- main loop ----------------
  for (int i = 0; i < TILES; ++i) {
    __builtin_amdgcn_s_barrier();   // xs(i) & hs(i-1) consumed (data-dep drained)
    epi1();                          // acc1 -> hs(i)
    if (i + 1 < TILES) stage();      // xv -> xs(i+1)
    {
      long nt = (long)(i + 2 < TILES ? i + 2 : TILES - 1);
      loadxv(tbase + nt);            // issue x(i+2) global loads (in flight)
    }
    prefL2();
    asm volatile("s_waitcnt lgkmcnt(0)" ::: "memory");
    __builtin_amdgcn_s_barrier();    // publish hs(i), xs(i+1)
    if (i + 1 < TILES) prefL1();     // weight frags for L1(i+1), fly under L2
    runL2();                         // acc2 for tile i
    // epilogue 2: out stores (fire and forget)
    {
      const long row0 = (tbase + i) * BM;
#pragma unroll
      for (int mf = 0; mf < 2; ++mf) {
        int nb = 32 * wv + 16 * mf + g * 4;
        float4 bb = *(const float4*)&b2[nb];
#pragma unroll
        for (int nf = 0; nf < 4; ++nf) {
          int m = nf * 16 + l15;
          f32x4 a = acc2[mf][nf];
          float4 o;
          o.x = s2 * a[0] + bb.x;
          o.y = s2 * a[1] + bb.y;
          o.z = s2 * a[2] + bb.z;
          o.w = s2 * a[3] + bb.w;
          *(float4*)&out[(row0 + m) * D_OUT + nb] = o;
        }
      }
    }
    if (i + 1 < TILES) runL1();      // tile i+1 (same MFMA region as L2(i))
  }
}

extern "C" void kernel_launch(void* const* d_in, const int* in_sizes, int n_in,
                              void* d_out, int out_size, void* d_ws, size_t ws_size,
                              hipStream_t stream) {
  const float* x  = (const float*)d_in[0];
  const float* W1 = (const float*)d_in[1];
  const float* b1 = (const float*)d_in[2];
  const float* W2 = (const float*)d_in[3];
  const float* b2 = (const float*)d_in[4];
  float* out = (float*)d_out;

  double* part = (double*)d_ws;
  float* fsc = (float*)((char*)d_ws + 128);
  unsigned short* w1c = (unsigned short*)((char*)d_ws + 1024);
  unsigned short* w2c = (unsigned short*)((char*)d_ws + 1024 + D_HID * D_IN * 2);

  int Brows = in_sizes[0] / D_IN;  // 262144
  int nblk = Brows / (BM * TILES); // 256

  partial_abs_kernel<<<dim3(16), dim3(1024), 0, stream>>>(W1, W2, part);
  quant_kernel<<<dim3(256), dim3(256), 0, stream>>>(W1, W2, part, w1c, w2c, fsc);
  fused_mlp<<<dim3(nblk), dim3(512), 0, stream>>>(x, b1, b2, w1c, w2c, fsc, out);
}